// Round 1
// 506.395 us; speedup vs baseline: 1.0133x; 1.0133x over previous
//
#include <hip/hip_runtime.h>

// C[b,i] = 0.125 * sum_k LI[X[b,8,3]][k] * IL[i][k]
// M=1024, N=100000, K=64.  Write-bound (409.6 MB out); bf16 MFMA for compute.
//
// This version: operand-swapped MFMA (lane = m, regs = 4 consecutive n) +
// LDS-transposed epilogue -> full-line (256B/row) dwordx4 nontemporal stores.

typedef short short8 __attribute__((ext_vector_type(8)));
typedef float f32x4 __attribute__((ext_vector_type(4)));
typedef unsigned short ushort4v __attribute__((ext_vector_type(4)));

#define KDIM 64
#define LDSS 72   // staging row stride in bf16 elems (144 B: 16B-aligned, 2-way alias only)
#define EPS  68   // epilogue scratch row stride in f32 (272 B = odd multiple of 16B -> conflict-free b128)

static __device__ __forceinline__ unsigned short f2bf(float f) {
    unsigned u = __float_as_uint(f);
    unsigned r = (u + 0x7fffu + ((u >> 16) & 1u)) >> 16;   // RNE
    return (unsigned short)r;
}

__global__ __launch_bounds__(256)
void fpmc_gemm(const int* __restrict__ X,
               const float* __restrict__ IL,
               const float* __restrict__ LI,
               float* __restrict__ out,
               int M, int N) {
    // Single SMEM block: staging tiles (bf16) and epilogue scratch (f32) overlay.
    // Staging: 2 * 128 * 72 * 2B = 36,864 B.  Scratch: 8 regions * 16*68*4B = 34,816 B.
    __shared__ __align__(16) unsigned short SMEM[2 * 128 * LDSS];
    unsigned short* As = SMEM;
    unsigned short* Bs = SMEM + 128 * LDSS;

    const int t  = threadIdx.x;
    const int m0 = blockIdx.y * 128;
    const int i0 = blockIdx.x * 128;

    // ---- stage A tile: gather LI rows via X, convert fp32->bf16 ----
    {
        const int rb = t >> 4;          // 0..15
        const int c  = (t & 15) * 4;    // 0..60 step 4
        #pragma unroll
        for (int it = 0; it < 8; ++it) {
            const int r = it * 16 + rb;                 // 0..127
            const int idx = X[(m0 + r) * 40 + 35];      // X[b, 8, 3]
            const float4 v = *(const float4*)(LI + (size_t)idx * KDIM + c);
            ushort4v p;
            p.x = f2bf(v.x); p.y = f2bf(v.y); p.z = f2bf(v.z); p.w = f2bf(v.w);
            *(ushort4v*)&As[r * LDSS + c] = p;
        }
    }
    // ---- stage B tile: IL rows i0..i0+127, convert fp32->bf16 ----
    {
        const int rb = t >> 4;
        const int c  = (t & 15) * 4;
        #pragma unroll
        for (int it = 0; it < 8; ++it) {
            const int r = it * 16 + rb;
            int gi = i0 + r;
            if (gi > N - 1) gi = N - 1;                 // clamp; stores guarded later
            const float4 v = *(const float4*)(IL + (size_t)gi * KDIM + c);
            ushort4v p;
            p.x = f2bf(v.x); p.y = f2bf(v.y); p.z = f2bf(v.z); p.w = f2bf(v.w);
            *(ushort4v*)&Bs[r * LDSS + c] = p;
        }
    }
    __syncthreads();

    // ---- compute: wave (w&1)->M half, (w>>1)->N half; 64x64 per wave ----
    const int w    = t >> 6;
    const int l    = t & 63;
    const int row  = l & 15;     // fragment row index (also: m within sub-tile for C)
    const int quad = l >> 4;     // 0..3
    const int mw   = (w & 1) * 64;
    const int nw   = (w >> 1) * 64;

    f32x4 acc[4][4];
    #pragma unroll
    for (int mt = 0; mt < 4; ++mt)
        #pragma unroll
        for (int nt = 0; nt < 4; ++nt)
            acc[mt][nt] = (f32x4){0.f, 0.f, 0.f, 0.f};

    #pragma unroll
    for (int ks = 0; ks < KDIM; ks += 32) {
        short8 a[4], b[4];
        #pragma unroll
        for (int mt = 0; mt < 4; ++mt)
            a[mt] = *(const short8*)&As[(mw + mt * 16 + row) * LDSS + ks + quad * 8];
        #pragma unroll
        for (int nt = 0; nt < 4; ++nt)
            b[nt] = *(const short8*)&Bs[(nw + nt * 16 + row) * LDSS + ks + quad * 8];
        // Operand swap: D-row index <- B operand (n), D-col index <- A operand (m).
        // Lane thus holds: m = mt*16 + (l&15), n = nt*16 + quad*4 + reg (4 consecutive n!).
        #pragma unroll
        for (int mt = 0; mt < 4; ++mt)
            #pragma unroll
            for (int nt = 0; nt < 4; ++nt)
                acc[mt][nt] = __builtin_amdgcn_mfma_f32_16x16x32_bf16(
                    b[nt], a[mt], acc[mt][nt], 0, 0, 0);
    }

    // ---- epilogue: transpose 16x64 sub-tiles through LDS scratch, then
    //      full-line contiguous dwordx4 nontemporal stores (4 rows x 256B per instr).
    float* T = reinterpret_cast<float*>(SMEM);
    const float scale = 0.125f;   // 1/sqrt(64)

    #pragma unroll
    for (int mb = 0; mb < 4; mb += 2) {
        __syncthreads();   // iter0: waves done reading As/Bs; iter1: scratch reads of iter0 done
        #pragma unroll
        for (int s = 0; s < 2; ++s) {
            float* Tw = T + (w * 2 + s) * (16 * EPS);
            #pragma unroll
            for (int nt = 0; nt < 4; ++nt) {
                f32x4 v = acc[mb + s][nt] * scale;
                // row m_local = (l&15), cols nt*16 + quad*4 .. +3
                *(f32x4*)&Tw[row * EPS + nt * 16 + quad * 4] = v;
            }
        }
        __syncthreads();
        #pragma unroll
        for (int s = 0; s < 2; ++s) {
            const float* Tw = T + (w * 2 + s) * (16 * EPS);
            const int gm = m0 + mw + (mb + s) * 16;
            const int n  = i0 + nw + row * 4;          // N % 4 == 0 -> whole-float4 guard
            #pragma unroll
            for (int p = 0; p < 4; ++p) {
                const int ml = p * 4 + quad;           // 0..15
                f32x4 v = *(const f32x4*)&Tw[ml * EPS + row * 4];
                if (n < N)
                    __builtin_nontemporal_store(
                        v, (f32x4*)(out + (size_t)(gm + ml) * N + n));
            }
        }
    }
}

extern "C" void kernel_launch(void* const* d_in, const int* in_sizes, int n_in,
                              void* d_out, int out_size, void* d_ws, size_t ws_size,
                              hipStream_t stream) {
    const int*   X  = (const int*)d_in[0];
    const float* IL = (const float*)d_in[1];
    const float* LI = (const float*)d_in[2];
    float* out = (float*)d_out;

    const int M = in_sizes[0] / 40;      // 1024
    const int N = in_sizes[1] / KDIM;    // 100000

    dim3 grid((N + 127) / 128, M / 128);
    fpmc_gemm<<<grid, dim3(256), 0, stream>>>(X, IL, LI, out, M, N);
}

// Round 3
// 484.084 us; speedup vs baseline: 1.0600x; 1.0461x over previous
//
#include <hip/hip_runtime.h>

// C[b,i] = 0.125 * sum_k LI[X[b,8,3]][k] * IL[i][k]
// M=1024, N=100000, K=64.  Write-bound (409.6 MB out).
//
// Structure (v2b): phase-1 gathers the 1024 LI rows via X into bf16 ws (128 KB, once).
// Phase-2: each block pins a 256-row A-slab in LDS, streams IL global->reg (bf16
// convert in-reg, no B staging), MFMAs against resident A, stores continuously (NT).
// Eliminates: 200 MB random gather, 8x IL re-read, B LDS round-trip, most barriers.

typedef short short8 __attribute__((ext_vector_type(8)));
typedef float f32x4 __attribute__((ext_vector_type(4)));
typedef unsigned short ushort4v __attribute__((ext_vector_type(4)));
typedef unsigned short ushort8v __attribute__((ext_vector_type(8)));

#define KDIM  64
#define LDSS  72     // padded LDS row stride in bf16 (144 B -> 2-way bank alias only, free)
#define MSLAB 256    // A rows resident in LDS per block
#define NSLAB 256    // output columns per block
#define NCH   32     // columns per inner chunk (acc = 4x2 f32x4 = 32 VGPR)

static __device__ __forceinline__ unsigned short f2bf(float f) {
    unsigned u = __float_as_uint(f);
    return (unsigned short)((u + 0x7fffu + ((u >> 16) & 1u)) >> 16);   // RNE
}

static __device__ __forceinline__ short8 cvt8(float4 v0, float4 v1) {
    union { ushort8v u; short8 s; } r;
    r.u[0] = f2bf(v0.x); r.u[1] = f2bf(v0.y); r.u[2] = f2bf(v0.z); r.u[3] = f2bf(v0.w);
    r.u[4] = f2bf(v1.x); r.u[5] = f2bf(v1.y); r.u[6] = f2bf(v1.z); r.u[7] = f2bf(v1.w);
    return r.s;
}

// ---- Phase 1: A[b][k] = bf16(LI[X[b,8,3]][k]) into ws. 64 blocks, ~5 us. ----
__global__ __launch_bounds__(256)
void fpmc_gather(const int* __restrict__ X, const float* __restrict__ LI,
                 unsigned short* __restrict__ ws, int M) {
    const int t = threadIdx.x;
    const int r = blockIdx.x * 16 + (t >> 4);
    if (r >= M) return;
    const int c = (t & 15) * 4;
    const int idx = X[r * 40 + 35];                    // X[b, 8, 3]
    const float4 v = *(const float4*)(LI + (size_t)idx * KDIM + c);
    ushort4v p;
    p.x = f2bf(v.x); p.y = f2bf(v.y); p.z = f2bf(v.z); p.w = f2bf(v.w);
    *(ushort4v*)(ws + (size_t)r * KDIM + c) = p;
}

// ---- Phase 2: stream IL, MFMA vs LDS-resident A-slab, NT stores. ----
template<bool USE_WS>
__global__ __launch_bounds__(256, 4)
void fpmc_gemm2(const int* __restrict__ X, const float* __restrict__ IL,
                const float* __restrict__ LI, const unsigned short* __restrict__ Aws,
                float* __restrict__ out, int M, int N) {
    __shared__ __align__(16) unsigned short As[MSLAB * LDSS];   // 36,864 B -> 4 blocks/CU

    const int t  = threadIdx.x;
    const int m0 = blockIdx.y * MSLAB;
    const int i0 = blockIdx.x * NSLAB;

    if (USE_WS) {
        // coalesced copy ws -> LDS: 2048 short8 chunks, 8 per thread
        #pragma unroll
        for (int it = 0; it < 8; ++it) {
            const int chunk = it * 256 + t;
            const int r = chunk >> 3;
            const int c = (chunk & 7) * 8;
            ushort8v v = *(const ushort8v*)(Aws + (size_t)(m0 + r) * KDIM + c);
            *(ushort8v*)&As[r * LDSS + c] = v;
        }
    } else {
        // fallback: in-block gather (ws too small)
        const int rb = t >> 4;
        const int c  = (t & 15) * 4;
        #pragma unroll
        for (int it = 0; it < MSLAB / 16; ++it) {
            const int r = it * 16 + rb;
            const int idx = X[(m0 + r) * 40 + 35];
            const float4 v = *(const float4*)(LI + (size_t)idx * KDIM + c);
            ushort4v p;
            p.x = f2bf(v.x); p.y = f2bf(v.y); p.z = f2bf(v.z); p.w = f2bf(v.w);
            *(ushort4v*)&As[r * LDSS + c] = p;
        }
    }
    __syncthreads();

    // wave w owns m-rows [w*64, w*64+64); loops over 8 chunks of 32 columns
    const int w    = t >> 6;
    const int l    = t & 63;
    const int lr   = l & 15;     // intrinsic-B col -> m;  intrinsic-A row -> n (for loads)
    const int quad = l >> 4;
    const int mwav = w * 64;
    const float scale = 0.125f;  // 1/sqrt(64)

    for (int nc = 0; nc < NSLAB / NCH; ++nc) {
        const int n0c = i0 + nc * NCH;

        f32x4 acc[4][2];
        #pragma unroll
        for (int mt = 0; mt < 4; ++mt)
            #pragma unroll
            for (int nt = 0; nt < 2; ++nt)
                acc[mt][nt] = (f32x4){0.f, 0.f, 0.f, 0.f};

        #pragma unroll
        for (int ks = 0; ks < 2; ++ks) {
            // B fragments: IL rows (= output cols), global->reg, convert in-reg.
            // lane holds IL row n0c+nt*16+(l&15), k = ks*32 + quad*8 .. +7
            short8 b[2];
            #pragma unroll
            for (int nt = 0; nt < 2; ++nt) {
                int n = n0c + nt * 16 + lr;
                if (n > N - 1) n = N - 1;              // clamp; stores guarded below
                const float* p = IL + (size_t)n * KDIM + ks * 32 + quad * 8;
                b[nt] = cvt8(*(const float4*)p, *(const float4*)(p + 4));
            }
            // A fragments from LDS-resident slab
            short8 a[4];
            #pragma unroll
            for (int mt = 0; mt < 4; ++mt)
                a[mt] = *(const short8*)&As[(mwav + mt * 16 + lr) * LDSS + ks * 32 + quad * 8];
            // operand swap: D col = m (lane&15), D row = n (quad*4+reg)
            #pragma unroll
            for (int mt = 0; mt < 4; ++mt)
                #pragma unroll
                for (int nt = 0; nt < 2; ++nt)
                    acc[mt][nt] = __builtin_amdgcn_mfma_f32_16x16x32_bf16(
                        b[nt], a[mt], acc[mt][nt], 0, 0, 0);
        }

        // stores: lane holds 4 consecutive n per (mt,nt) -> f32x4 NT store
        #pragma unroll
        for (int mt = 0; mt < 4; ++mt) {
            const int m = m0 + mwav + mt * 16 + lr;
            if (m >= M) continue;                      // defensive (M % MSLAB == 0 in practice)
            float* orow = out + (size_t)m * N;
            #pragma unroll
            for (int nt = 0; nt < 2; ++nt) {
                const int n = n0c + nt * 16 + quad * 4;
                if (n < N) {
                    f32x4 v = acc[mt][nt] * scale;
                    __builtin_nontemporal_store(v, (f32x4*)(orow + n));
                }
            }
        }
    }
}

extern "C" void kernel_launch(void* const* d_in, const int* in_sizes, int n_in,
                              void* d_out, int out_size, void* d_ws, size_t ws_size,
                              hipStream_t stream) {
    const int*   X  = (const int*)d_in[0];
    const float* IL = (const float*)d_in[1];
    const float* LI = (const float*)d_in[2];
    float* out = (float*)d_out;

    const int M = in_sizes[0] / 40;      // 1024
    const int N = in_sizes[1] / KDIM;    // 100000

    unsigned short* Aws = (unsigned short*)d_ws;
    const size_t need = (size_t)M * KDIM * sizeof(unsigned short);   // 128 KB

    dim3 grid((N + NSLAB - 1) / NSLAB, (M + MSLAB - 1) / MSLAB);
    if (d_ws != nullptr && ws_size >= need) {
        fpmc_gather<<<dim3((M + 15) / 16), dim3(256), 0, stream>>>(X, LI, Aws, M);
        fpmc_gemm2<true><<<grid, dim3(256), 0, stream>>>(X, IL, LI, Aws, out, M, N);
    } else {
        fpmc_gemm2<false><<<grid, dim3(256), 0, stream>>>(X, IL, LI, Aws, out, M, N);
    }
}